// Round 15
// baseline (2097.758 us; speedup 1.0000x reference)
//
#include <hip/hip_runtime.h>
#include <stdint.h>
#include <math.h>

#define NB 4
#define CIN 512
#define CMID 512
#define HH 50
#define WW 50
#define NPIX 2500
#define AA 9
#define RR 22500
#define PB 6000
#define PA 300
#define LOCCH 36
#define SCORECH 18
#define HEADCH 54
#define CI_T 8
#define CI_T2 4
#define SUPR 1500
#define SUPW 188
#define JWIN 1024

typedef unsigned long long u64;

// ---------------- conv v12: v9 structure, full K, fused bias+relu ----------------
// grid (49, 8, nb), block 128. Thread: 4co x 8col. CI_T2=4, LDS 13KB.
// Per-output FMA chain: cc 0..512 ascending, ci, ky, kx — the R5-verified order.
__global__ __launch_bounds__(128) void conv3_f64_v12(
    const float* __restrict__ x, const float* __restrict__ w1,
    const float* __restrict__ b1, double* __restrict__ inter) {
    __shared__ __align__(16) double xs[CI_T2 * 100];
    __shared__ __align__(16) float wsf[CI_T2 * 9 * 68];

    int tile = blockIdx.x;
    int ty = tile / 7, tx = tile % 7;
    int co0 = blockIdx.y * 64;
    int bz = blockIdx.z;
    int tid = threadIdx.x;
    int tm = tid & 15;
    int pyt = tid >> 4;
    int gy0 = ty * 8, gx0 = tx * 8;
    const float* xb = x + (size_t)bz * CIN * NPIX;

    // hoisted x-staging indices (chunk-invariant)
    int xg[4];
    #pragma unroll
    for (int k = 0; k < 4; ++k) {
        int e = tid + k * 128;
        if (e < CI_T2 * 100) {
            int ci = e / 100, rc = e % 100;
            int row = rc / 10, col = rc % 10;
            int gy = gy0 - 1 + row, gx = gx0 - 1 + col;
            xg[k] = (gy >= 0 && gy < HH && gx >= 0 && gx < WW)
                        ? (ci * NPIX + gy * WW + gx) : -1;
        } else {
            xg[k] = -1;
        }
    }
    // weight staging bases (chunk-invariant except +cc*9)
    int wm = tid >> 1;               // co-local 0..63
    int wq0 = (tid & 1) * 18;        // q half 0 or 18
    const float* wrow = w1 + (size_t)(co0 + wm) * (CIN * 9) + wq0;
    float* wdst = &wsf[wq0 * 68 + wm];

    double acc[4][8] = {};

    for (int cc = 0; cc < CIN; cc += CI_T2) {
        // ---- stage x (4ci x 10x10): no index math
        size_t xoff = (size_t)cc * NPIX;
        #pragma unroll
        for (int k = 0; k < 4; ++k) {
            int e = tid + k * 128;
            if (e < CI_T2 * 100) {
                float v = (xg[k] >= 0) ? xb[xoff + xg[k]] : 0.f;
                xs[e] = (double)v;
            }
        }
        // ---- stage w: 18 copies, immediate offsets
        {
            const float* ws = wrow + (size_t)cc * 9;
            #pragma unroll
            for (int k = 0; k < 18; ++k)
                wdst[k * 68] = ws[k];
        }
        __syncthreads();

        for (int ci = 0; ci < CI_T2; ++ci) {
            #pragma unroll
            for (int ky = 0; ky < 3; ++ky) {
                double xa[10];
                const double* xr = &xs[ci * 100 + (pyt + ky) * 10];
                #pragma unroll
                for (int t = 0; t < 5; ++t)
                    *(double2*)&xa[2 * t] = *(const double2*)&xr[2 * t];
                #pragma unroll
                for (int kx = 0; kx < 3; ++kx) {
                    float4 wf = *(const float4*)&wsf[(ci * 9 + ky * 3 + kx) * 68 + tm * 4];
                    double w0 = (double)wf.x, w1v = (double)wf.y;
                    double w2 = (double)wf.z, w3 = (double)wf.w;
                    #pragma unroll
                    for (int j = 0; j < 8; ++j) {
                        double xv = xa[kx + j];
                        acc[0][j] = fma(w0, xv, acc[0][j]);
                        acc[1][j] = fma(w1v, xv, acc[1][j]);
                        acc[2][j] = fma(w2, xv, acc[2][j]);
                        acc[3][j] = fma(w3, xv, acc[3][j]);
                    }
                }
            }
        }
        __syncthreads();
    }

    int gy = gy0 + pyt;
    if (gy < HH) {
        double* ib = inter + (size_t)bz * CMID * NPIX;
        #pragma unroll
        for (int i = 0; i < 4; ++i) {
            int co = co0 + tm * 4 + i;
            double bias = (double)b1[co];
            #pragma unroll
            for (int j = 0; j < 8; ++j) {
                int gx = gx0 + j;
                if (gx < WW) {
                    double v = fmax(acc[i][j] + bias, 0.0);
                    ib[(size_t)co * NPIX + gy * WW + gx] = v;
                }
            }
        }
    }
}

// ---------------- fallback conv (R5's v3, bit-verified) ----------------
__global__ __launch_bounds__(256) void conv3_f64_v3(
    const float* __restrict__ x, const float* __restrict__ w1,
    const float* __restrict__ b1, double* __restrict__ inter, int nbase) {
    __shared__ __align__(16) double xs[CI_T][10][10];
    __shared__ __align__(16) float wsf[CI_T * 9][68];

    int tile = blockIdx.x;
    int ty = tile / 7, tx = tile % 7;
    int co0 = blockIdx.y * 64;
    int bz = blockIdx.z;
    int n = nbase + bz;
    int tid = threadIdx.x;
    int tm = tid & 15;
    int tp = tid >> 4;
    int pyt = tp >> 1;
    int px0 = (tp & 1) * 4;
    int gy0 = ty * 8, gx0 = tx * 8;
    const float* xb = x + (size_t)n * CIN * NPIX;
    double* ib = inter + (size_t)bz * CMID * NPIX;

    double acc[4][4] = {};

    for (int cc = 0; cc < CIN; cc += CI_T) {
        for (int e = tid; e < CI_T * 100; e += 256) {
            int ci = e / 100, rc = e % 100;
            int row = rc / 10, col = rc % 10;
            int gy = gy0 - 1 + row, gx = gx0 - 1 + col;
            float v = 0.f;
            if (gy >= 0 && gy < HH && gx >= 0 && gx < WW)
                v = xb[(size_t)(cc + ci) * NPIX + gy * WW + gx];
            xs[ci][row][col] = (double)v;
        }
        for (int e = tid; e < 64 * 72; e += 256) {
            int m = e / 72, q = e % 72;
            wsf[q][m] = w1[((size_t)(co0 + m) * CIN + cc) * 9 + q];
        }
        __syncthreads();

        for (int ci = 0; ci < CI_T; ++ci) {
            #pragma unroll
            for (int ky = 0; ky < 3; ++ky) {
                double xa[6];
                const double* xrow = &xs[ci][pyt + ky][px0];
                *(double2*)&xa[0] = *(const double2*)&xrow[0];
                *(double2*)&xa[2] = *(const double2*)&xrow[2];
                *(double2*)&xa[4] = *(const double2*)&xrow[4];
                #pragma unroll
                for (int kx = 0; kx < 3; ++kx) {
                    float4 wf = *(const float4*)&wsf[ci * 9 + ky * 3 + kx][tm * 4];
                    double w0 = (double)wf.x, w1v = (double)wf.y;
                    double w2 = (double)wf.z, w3 = (double)wf.w;
                    #pragma unroll
                    for (int j = 0; j < 4; ++j) {
                        double xv = xa[kx + j];
                        acc[0][j] = fma(w0, xv, acc[0][j]);
                        acc[1][j] = fma(w1v, xv, acc[1][j]);
                        acc[2][j] = fma(w2, xv, acc[2][j]);
                        acc[3][j] = fma(w3, xv, acc[3][j]);
                    }
                }
            }
        }
        __syncthreads();
    }

    int gy = gy0 + pyt;
    #pragma unroll
    for (int i = 0; i < 4; ++i) {
        int co = co0 + tm * 4 + i;
        double bias = (double)b1[co];
        #pragma unroll
        for (int j = 0; j < 4; ++j) {
            int gx = gx0 + px0 + j;
            if (gy < HH && gx < WW) {
                double v = fmax(acc[i][j] + bias, 0.0);
                ib[(size_t)co * NPIX + gy * WW + gx] = v;
            }
        }
    }
}

// ---------------- 1x1 heads, f64 (single inter buffer) ----------------
#define HP 64
#define HCI 32
__global__ __launch_bounds__(128) void heads_kernel_f64(
    const double* __restrict__ inter,
    const float* __restrict__ w_loc, const float* __restrict__ b_loc,
    const float* __restrict__ w_score, const float* __restrict__ b_score,
    double* __restrict__ loc64, double* __restrict__ score64,
    float* __restrict__ out_loc, float* __restrict__ out_score, int nbase) {
    __shared__ double xsh[HCI][HP];
    __shared__ double wsh[HEADCH][HCI];
    int bz = blockIdx.y;
    int n = nbase + bz;
    const double* ib = inter + (size_t)bz * CMID * NPIX;
    int p0 = blockIdx.x * HP;
    int tid = threadIdx.x;
    int pl = tid & 63;
    int g = tid >> 6;
    double acc[27] = {};

    for (int cc = 0; cc < CMID; cc += HCI) {
        for (int e = tid; e < HCI * HP; e += 128) {
            int p = e % HP;
            int ci = e / HP;
            int gp = p0 + p;
            xsh[ci][p] = (gp < NPIX) ? ib[(size_t)(cc + ci) * NPIX + gp] : 0.0;
        }
        for (int e = tid; e < HEADCH * HCI; e += 128) {
            int ci = e % HCI;
            int u = e / HCI;
            float wv = (u < LOCCH) ? w_loc[(size_t)u * CMID + cc + ci]
                                   : w_score[(size_t)(u - LOCCH) * CMID + cc + ci];
            wsh[u][ci] = (double)wv;
        }
        __syncthreads();
        for (int ci = 0; ci < HCI; ++ci) {
            double xv = xsh[ci][pl];
            #pragma unroll
            for (int o = 0; o < 27; ++o)
                acc[o] = fma(wsh[g * 27 + o][ci], xv, acc[o]);
        }
        __syncthreads();
    }

    int gp = p0 + pl;
    if (gp < NPIX) {
        #pragma unroll
        for (int o = 0; o < 27; ++o) {
            int u = g * 27 + o;
            if (u < LOCCH) {
                double v = acc[o] + (double)b_loc[u];
                loc64[(size_t)n * RR * 4 + (size_t)gp * 36 + u] = v;
                out_loc[(size_t)n * RR * 4 + (size_t)gp * 36 + u] = (float)v;
            } else {
                int us = u - LOCCH;
                double v = acc[o] + (double)b_score[us];
                score64[(size_t)n * RR * 2 + (size_t)gp * 18 + us] = v;
                out_score[(size_t)n * RR * 2 + (size_t)gp * 18 + us] = (float)v;
            }
        }
    }
}

// ---------------- anchors + decode + softmax-fg + keys, f64 ----------------
__global__ void box_kernel_f64_v2(const double* __restrict__ loc64,
                                  const double* __restrict__ score64,
                                  float* __restrict__ out_anchor,
                                  const int* __restrict__ imh_p, const int* __restrict__ imw_p,
                                  double* __restrict__ boxes, u64* __restrict__ keys) {
    int idx = blockIdx.x * 256 + threadIdx.x;
    if (idx >= NB * RR) return;
    int r = idx % RR;
    int a = r % AA;
    int pp = r / AA;
    int gy = pp / WW, gx = pp % WW;
    int ri = a / 3, si = a % 3;
    const double ratios[3] = {0.5, 1.0, 2.0};
    const double scales[3] = {8.0, 16.0, 32.0};
    double hh = 16.0 * sqrt(ratios[ri]) * scales[si];
    double ww = 16.0 * sqrt(1.0 / ratios[ri]) * scales[si];
    float sy = (float)(gy * 16), sx = (float)(gx * 16);
    float a0f = (float)(8.0 - hh * 0.5) + sy;
    float a1f = (float)(8.0 - ww * 0.5) + sx;
    float a2f = (float)(8.0 + hh * 0.5) + sy;
    float a3f = (float)(8.0 + ww * 0.5) + sx;
    if (idx < RR) {
        float* o = out_anchor + (size_t)r * 4;
        o[0] = a0f; o[1] = a1f; o[2] = a2f; o[3] = a3f;
    }
    double a0 = (double)a0f, a1 = (double)a1f, a2 = (double)a2f, a3 = (double)a3f;

    const double* l = loc64 + (size_t)idx * 4;
    double ah = a2 - a0, aw = a3 - a1;
    double acy = a0 + 0.5 * ah, acx = a1 + 0.5 * aw;
    double cy = l[0] * ah + acy, cx = l[1] * aw + acx;
    double h = exp(l[2]) * ah, w = exp(l[3]) * aw;
    double imh = (double)imh_p[0], imw = (double)imw_p[0];
    double y1 = fmin(fmax(cy - 0.5 * h, 0.0), imh);
    double x1 = fmin(fmax(cx - 0.5 * w, 0.0), imw);
    double y2 = fmin(fmax(cy + 0.5 * h, 0.0), imh);
    double x2 = fmin(fmax(cx + 0.5 * w, 0.0), imw);
    bool valid = ((y2 - y1) >= 16.0) && ((x2 - x1) >= 16.0);
    double* b = boxes + (size_t)idx * 4;
    b[0] = y1; b[1] = x1; b[2] = y2; b[3] = x2;
    double s0 = score64[(size_t)idx * 2];
    double s1 = score64[(size_t)idx * 2 + 1];
    double m = fmax(s0, s1);
    double e0 = exp(s0 - m), e1 = exp(s1 - m);
    double sc = valid ? (e1 / (e0 + e1)) : -__builtin_inf();
    u64 bits = (u64)__double_as_longlong(sc);
    u64 t = (bits >> 63) ? ~bits : (bits | 0x8000000000000000ull);
    keys[idx] = (t & 0xFFFFFFFFFFFF8000ull) | (u64)(32767 - r);
}

// ---------------- top-6000 select + full sort (per batch) ----------------
__global__ __launch_bounds__(1024) void select_kernel(
    const u64* __restrict__ keys, const double* __restrict__ boxes,
    double* __restrict__ sbox, int* __restrict__ sval) {
    __shared__ unsigned int hist[256];
    __shared__ u64 cand[8192];
    __shared__ unsigned int s_sel, s_base, s_cnt;
    int n = blockIdx.x;
    int tid = threadIdx.x;
    const u64* k = keys + (size_t)n * RR;

    u64 prefix = 0;
    unsigned int base = 0;
    for (int round = 0; round < 3; ++round) {
        if (tid < 256) hist[tid] = 0;
        __syncthreads();
        int shift_match = 64 - 8 * round;
        int shift_bin = 56 - 8 * round;
        for (int r = tid; r < RR; r += 1024) {
            u64 kv = k[r];
            bool match = (round == 0) || ((kv >> shift_match) == prefix);
            if (match) atomicAdd(&hist[(unsigned int)((kv >> shift_bin) & 0xFF)], 1u);
        }
        __syncthreads();
        if (tid == 0) {
            unsigned int c = base;
            int sel = 0;
            for (int v = 255; v >= 0; --v) {
                if (c + hist[v] >= PB) { sel = v; break; }
                c += hist[v];
            }
            s_sel = (unsigned int)sel;
            s_base = c;
        }
        __syncthreads();
        prefix = (prefix << 8) | (u64)s_sel;
        base = s_base;
        __syncthreads();
    }

    if (tid == 0) s_cnt = 0;
    __syncthreads();
    for (int r = tid; r < RR; r += 1024) {
        u64 kv = k[r];
        if ((kv >> 40) >= prefix) {
            unsigned int pos = atomicAdd(&s_cnt, 1u);
            if (pos < 8192u) cand[pos] = kv;
        }
    }
    __syncthreads();
    unsigned int cnt = s_cnt;
    if (cnt > 8192u) cnt = 8192u;
    for (unsigned int i = cnt + tid; i < 8192u; i += 1024u) cand[i] = 0ull;
    __syncthreads();

    for (unsigned int kk = 2; kk <= 8192; kk <<= 1) {
        for (unsigned int j = kk >> 1; j > 0; j >>= 1) {
            for (unsigned int t = tid; t < 4096; t += 1024) {
                unsigned int i = ((t & ~(j - 1)) << 1) | (t & (j - 1));
                unsigned int l = i | j;
                u64 a = cand[i], b = cand[l];
                bool desc = ((i & kk) == 0);
                if ((a < b) == desc) { cand[i] = b; cand[l] = a; }
            }
            __syncthreads();
        }
    }

    for (int s = tid; s < PB; s += 1024) {
        u64 kv = cand[s];
        int valid = (int)(kv >> 63);
        double b0 = 0.0, b1 = 0.0, b2 = 0.0, b3 = 0.0;
        if (valid) {
            int r = 32767 - (int)(kv & 0x7FFFull);
            const double* bp = boxes + ((size_t)n * RR + r) * 4;
            b0 = bp[0]; b1 = bp[1]; b2 = bp[2]; b3 = bp[3];
        }
        double* sp = sbox + ((size_t)n * PB + s) * 4;
        sp[0] = b0; sp[1] = b1; sp[2] = b2; sp[3] = b3;
        sval[n * PB + s] = valid;
    }
}

// ---------------- NMS phase 1: suppression bitmask matrix for rows i < SUPR ----------------
__global__ __launch_bounds__(256) void nms_matrix(
    const double* __restrict__ sbox, unsigned int* __restrict__ sup) {
    __shared__ double jb[JWIN * 4];
    const int nrt = (SUPR + 31) / 32;
    const int njw_c = (PB + JWIN - 1) / JWIN;
    int bid = blockIdx.x;
    int n = bid / (nrt * njw_c);
    int rem = bid % (nrt * njw_c);
    int rt = rem / njw_c, jw = rem % njw_c;
    int tid = threadIdx.x;
    int j0 = jw * JWIN;

    for (int e = tid; e < JWIN * 4; e += 256) {
        int j = j0 + (e >> 2);
        jb[e] = (j < PB) ? sbox[((size_t)n * PB + j) * 4 + (e & 3)] : 0.0;
    }
    __syncthreads();

    int r = tid >> 3;
    int wq = tid & 7;
    int i = rt * 32 + r;
    if (i >= SUPR) return;
    const double* bi = sbox + ((size_t)n * PB + i) * 4;
    double y1 = bi[0], x1 = bi[1], y2 = bi[2], x2 = bi[3];
    double ai = (y2 - y1) * (x2 - x1);
    unsigned int* srow = sup + ((size_t)n * SUPR + i) * SUPW;

    #pragma unroll
    for (int q = 0; q < 4; ++q) {
        int wloc = wq * 4 + q;
        int w = jw * 32 + wloc;
        if (w >= SUPW) continue;
        unsigned int m = 0;
        int jbase = w * 32;
        for (int b = 0; b < 32; ++b) {
            int j = jbase + b;
            if (j <= i || j >= PB) continue;
            const double* bj = &jb[(size_t)(j - j0) * 4];
            double ty = fmax(y1, bj[0]);
            double tx = fmax(x1, bj[1]);
            double by = fmin(y2, bj[2]);
            double bx = fmin(x2, bj[3]);
            double ih = fmax(by - ty, 0.0);
            double iw = fmax(bx - tx, 0.0);
            double inter = ih * iw;
            double aj = (bj[2] - bj[0]) * (bj[3] - bj[1]);
            if (inter > 0.7 * (ai + aj - inter + 1e-9)) m |= (1u << b);
        }
        srow[w] = m;
    }
}

// ---------------- NMS phase 2: single-wave greedy scan over bitmask ----------------
__global__ __launch_bounds__(64) void nms_scan(
    const double* __restrict__ sbox, const int* __restrict__ sval,
    const unsigned int* __restrict__ sup,
    float* __restrict__ rois, float* __restrict__ rind) {
    __shared__ unsigned int keepw[SUPW];
    int n = blockIdx.x;
    int lane = threadIdx.x;

    for (int w = lane; w < SUPW; w += 64) {
        unsigned int m = 0;
        for (int b = 0; b < 32; ++b) {
            int j = w * 32 + b;
            if (j < PB && sval[n * PB + j]) m |= (1u << b);
        }
        keepw[w] = m;
    }
    __syncthreads();

    int kc = 0;
    for (int wi = 0; wi < SUPW && kc < PA; ++wi) {
        unsigned int word = keepw[wi];
        while (word) {
            int b = __ffs(word) - 1;
            int i = (wi << 5) + b;
            if (lane == 0) {
                const double* bp = sbox + ((size_t)n * PB + i) * 4;
                float* rp = rois + ((size_t)n * PA + kc) * 4;
                rp[0] = (float)bp[0]; rp[1] = (float)bp[1];
                rp[2] = (float)bp[2]; rp[3] = (float)bp[3];
            }
            ++kc;
            if (kc >= PA) break;
            if (i < SUPR) {
                const unsigned int* srow = sup + ((size_t)n * SUPR + i) * SUPW;
                #pragma unroll
                for (int t = 0; t < 3; ++t) {
                    int w2 = lane + t * 64;
                    if (w2 < SUPW) keepw[w2] &= ~srow[w2];
                }
            } else {
                const double* bp = sbox + ((size_t)n * PB + i) * 4;
                double y1 = bp[0], x1 = bp[1], y2 = bp[2], x2 = bp[3];
                double ai = (y2 - y1) * (x2 - x1);
                for (int j = i + 1 + lane; j < PB; j += 64) {
                    if (!((keepw[j >> 5] >> (j & 31)) & 1u)) continue;
                    const double* bj = sbox + ((size_t)n * PB + j) * 4;
                    double ty = fmax(y1, bj[0]);
                    double tx = fmax(x1, bj[1]);
                    double by = fmin(y2, bj[2]);
                    double bx = fmin(x2, bj[3]);
                    double ih = fmax(by - ty, 0.0);
                    double iw = fmax(bx - tx, 0.0);
                    double inter = ih * iw;
                    double aj = (bj[2] - bj[0]) * (bj[3] - bj[1]);
                    if (inter > 0.7 * (ai + aj - inter + 1e-9))
                        atomicAnd(&keepw[j >> 5], ~(1u << (j & 31)));
                }
            }
            __syncthreads();
            word = keepw[wi] & ((b >= 31) ? 0u : (0xFFFFFFFFu << (b + 1)));
        }
    }
    __syncthreads();

    for (int p = kc + lane; p < PA; p += 64) {
        float* rp = rois + ((size_t)n * PA + p) * 4;
        rp[0] = 0.f; rp[1] = 0.f; rp[2] = 0.f; rp[3] = 0.f;
    }
    for (int p = lane; p < PA; p += 64)
        rind[n * PA + p] = (float)n;
}

// ---------------- launch ----------------
extern "C" void kernel_launch(void* const* d_in, const int* in_sizes, int n_in,
                              void* d_out, int out_size, void* d_ws, size_t ws_size,
                              hipStream_t stream) {
    const float* x = (const float*)d_in[0];
    const float* w1 = (const float*)d_in[1];
    const float* b1 = (const float*)d_in[2];
    const float* w_score = (const float*)d_in[3];
    const float* b_score = (const float*)d_in[4];
    const float* w_loc = (const float*)d_in[5];
    const float* b_loc = (const float*)d_in[6];
    const int* img_h = (const int*)d_in[7];
    const int* img_w = (const int*)d_in[8];

    float* out = (float*)d_out;
    float* out_loc = out;
    float* out_score = out + 360000;
    float* out_rois = out + 540000;
    float* out_rind = out + 544800;
    float* out_anchor = out + 546000;

    const size_t interB = (size_t)NB * CMID * NPIX * 8;     // 40,960,000
    const size_t interB_serial = (size_t)CMID * NPIX * 8;   // 10,240,000
    const size_t restB = 2880000 + 1440000 + 2880000 + 720000 + 768000 + 96000;

    bool batched = ws_size >= interB + restB;
    size_t convB = batched ? interB : interB_serial;

    char* p = (char*)d_ws;
    double* conv_buf = (double*)p; p += convB;
    double* loc64   = (double*)p; p += 2880000;
    double* score64 = (double*)p; p += 1440000;
    double* boxes64 = (double*)p; p += 2880000;
    u64*    keys    = (u64*)p;    p += 720000;
    double* sbox64  = (double*)p; p += 768000;
    int*    sval    = (int*)p;

    unsigned int* sup = (unsigned int*)conv_buf;   // 4.5 MB, conv_buf dead after heads

    if (batched) {
        hipLaunchKernelGGL(conv3_f64_v12, dim3(49, 8, NB), dim3(128), 0, stream,
                           x, w1, b1, conv_buf);
        hipLaunchKernelGGL(heads_kernel_f64, dim3(40, NB), dim3(128), 0, stream,
                           conv_buf, w_loc, b_loc, w_score, b_score,
                           loc64, score64, out_loc, out_score, 0);
    } else {
        for (int n = 0; n < NB; ++n) {
            hipLaunchKernelGGL(conv3_f64_v3, dim3(49, 8, 1), dim3(256), 0, stream,
                               x, w1, b1, conv_buf, n);
            hipLaunchKernelGGL(heads_kernel_f64, dim3(40, 1), dim3(128), 0, stream,
                               conv_buf, w_loc, b_loc, w_score, b_score,
                               loc64, score64, out_loc, out_score, n);
        }
    }

    hipLaunchKernelGGL(box_kernel_f64_v2, dim3((NB * RR + 255) / 256), dim3(256), 0, stream,
                       loc64, score64, out_anchor, img_h, img_w, boxes64, keys);
    hipLaunchKernelGGL(select_kernel, dim3(4), dim3(1024), 0, stream, keys, boxes64, sbox64, sval);

    const int nrt = (SUPR + 31) / 32;
    const int njw = (PB + JWIN - 1) / JWIN;
    hipLaunchKernelGGL(nms_matrix, dim3(NB * nrt * njw), dim3(256), 0, stream, sbox64, sup);
    hipLaunchKernelGGL(nms_scan, dim3(NB), dim3(64), 0, stream, sbox64, sval, sup,
                       out_rois, out_rind);
}

// Round 16
// 1642.248 us; speedup vs baseline: 1.2774x; 1.2774x over previous
//
#include <hip/hip_runtime.h>
#include <stdint.h>
#include <math.h>

#define NB 4
#define CIN 512
#define CMID 512
#define HH 50
#define WW 50
#define NPIX 2500
#define AA 9
#define RR 22500
#define PB 6000
#define PA 300
#define LOCCH 36
#define SCORECH 18
#define HEADCH 54
#define CI_T 8
#define CI_T2 4
#define SUPK 1024
#define KW1 32
#define KW2 ((PB - SUPK + 31) / 32)

typedef unsigned long long u64;

// ---------------- conv v9 (R12-verified): split-K=2, zero-arithmetic staging --------
__global__ __launch_bounds__(128) void conv3_f64_v9(
    const float* __restrict__ x, const float* __restrict__ w1,
    double* __restrict__ part) {
    __shared__ __align__(16) double xs[CI_T2 * 100];
    __shared__ __align__(16) float wsf[CI_T2 * 9 * 68];

    int tile = blockIdx.x;
    int ty = tile / 7, tx = tile % 7;
    int yy = blockIdx.y;
    int co0 = (yy & 7) * 64;
    int kk = yy >> 3;
    int bz = blockIdx.z;
    int tid = threadIdx.x;
    int tm = tid & 15;
    int pyt = tid >> 4;
    int gy0 = ty * 8, gx0 = tx * 8;
    const float* xb = x + (size_t)bz * CIN * NPIX;
    int cc0 = kk * 256;

    int xg[4];
    #pragma unroll
    for (int k = 0; k < 4; ++k) {
        int e = tid + k * 128;
        if (e < CI_T2 * 100) {
            int ci = e / 100, rc = e % 100;
            int row = rc / 10, col = rc % 10;
            int gy = gy0 - 1 + row, gx = gx0 - 1 + col;
            xg[k] = (gy >= 0 && gy < HH && gx >= 0 && gx < WW)
                        ? (ci * NPIX + gy * WW + gx) : -1;
        } else {
            xg[k] = -1;
        }
    }
    int wm = tid >> 1;
    int wq0 = (tid & 1) * 18;
    const float* wrow = w1 + (size_t)(co0 + wm) * (CIN * 9) + wq0;
    float* wdst = &wsf[wq0 * 68 + wm];

    double acc[4][8] = {};

    for (int cc = cc0; cc < cc0 + 256; cc += CI_T2) {
        size_t xoff = (size_t)cc * NPIX;
        #pragma unroll
        for (int k = 0; k < 4; ++k) {
            int e = tid + k * 128;
            if (e < CI_T2 * 100) {
                float v = (xg[k] >= 0) ? xb[xoff + xg[k]] : 0.f;
                xs[e] = (double)v;
            }
        }
        {
            const float* ws = wrow + (size_t)cc * 9;
            #pragma unroll
            for (int k = 0; k < 18; ++k)
                wdst[k * 68] = ws[k];
        }
        __syncthreads();

        for (int ci = 0; ci < CI_T2; ++ci) {
            #pragma unroll
            for (int ky = 0; ky < 3; ++ky) {
                double xa[10];
                const double* xr = &xs[ci * 100 + (pyt + ky) * 10];
                #pragma unroll
                for (int t = 0; t < 5; ++t)
                    *(double2*)&xa[2 * t] = *(const double2*)&xr[2 * t];
                #pragma unroll
                for (int kx = 0; kx < 3; ++kx) {
                    float4 wf = *(const float4*)&wsf[(ci * 9 + ky * 3 + kx) * 68 + tm * 4];
                    double w0 = (double)wf.x, w1v = (double)wf.y;
                    double w2 = (double)wf.z, w3 = (double)wf.w;
                    #pragma unroll
                    for (int j = 0; j < 8; ++j) {
                        double xv = xa[kx + j];
                        acc[0][j] = fma(w0, xv, acc[0][j]);
                        acc[1][j] = fma(w1v, xv, acc[1][j]);
                        acc[2][j] = fma(w2, xv, acc[2][j]);
                        acc[3][j] = fma(w3, xv, acc[3][j]);
                    }
                }
            }
        }
        __syncthreads();
    }

    int gy = gy0 + pyt;
    if (gy < HH) {
        double* pb = part + (size_t)kk * NB * CMID * NPIX + (size_t)bz * CMID * NPIX;
        #pragma unroll
        for (int i = 0; i < 4; ++i) {
            int co = co0 + tm * 4 + i;
            #pragma unroll
            for (int j = 0; j < 8; ++j) {
                int gx = gx0 + j;
                if (gx < WW)
                    pb[(size_t)co * NPIX + gy * WW + gx] = acc[i][j];
            }
        }
    }
}

// ---------------- fallback conv (R5's v3, bit-verified) ----------------
__global__ __launch_bounds__(256) void conv3_f64_v3(
    const float* __restrict__ x, const float* __restrict__ w1,
    const float* __restrict__ b1, double* __restrict__ inter, int nbase) {
    __shared__ __align__(16) double xs[CI_T][10][10];
    __shared__ __align__(16) float wsf[CI_T * 9][68];

    int tile = blockIdx.x;
    int ty = tile / 7, tx = tile % 7;
    int co0 = blockIdx.y * 64;
    int bz = blockIdx.z;
    int n = nbase + bz;
    int tid = threadIdx.x;
    int tm = tid & 15;
    int tp = tid >> 4;
    int pyt = tp >> 1;
    int px0 = (tp & 1) * 4;
    int gy0 = ty * 8, gx0 = tx * 8;
    const float* xb = x + (size_t)n * CIN * NPIX;
    double* ib = inter + (size_t)bz * CMID * NPIX;

    double acc[4][4] = {};

    for (int cc = 0; cc < CIN; cc += CI_T) {
        for (int e = tid; e < CI_T * 100; e += 256) {
            int ci = e / 100, rc = e % 100;
            int row = rc / 10, col = rc % 10;
            int gy = gy0 - 1 + row, gx = gx0 - 1 + col;
            float v = 0.f;
            if (gy >= 0 && gy < HH && gx >= 0 && gx < WW)
                v = xb[(size_t)(cc + ci) * NPIX + gy * WW + gx];
            xs[ci][row][col] = (double)v;
        }
        for (int e = tid; e < 64 * 72; e += 256) {
            int m = e / 72, q = e % 72;
            wsf[q][m] = w1[((size_t)(co0 + m) * CIN + cc) * 9 + q];
        }
        __syncthreads();

        for (int ci = 0; ci < CI_T; ++ci) {
            #pragma unroll
            for (int ky = 0; ky < 3; ++ky) {
                double xa[6];
                const double* xrow = &xs[ci][pyt + ky][px0];
                *(double2*)&xa[0] = *(const double2*)&xrow[0];
                *(double2*)&xa[2] = *(const double2*)&xrow[2];
                *(double2*)&xa[4] = *(const double2*)&xrow[4];
                #pragma unroll
                for (int kx = 0; kx < 3; ++kx) {
                    float4 wf = *(const float4*)&wsf[ci * 9 + ky * 3 + kx][tm * 4];
                    double w0 = (double)wf.x, w1v = (double)wf.y;
                    double w2 = (double)wf.z, w3 = (double)wf.w;
                    #pragma unroll
                    for (int j = 0; j < 4; ++j) {
                        double xv = xa[kx + j];
                        acc[0][j] = fma(w0, xv, acc[0][j]);
                        acc[1][j] = fma(w1v, xv, acc[1][j]);
                        acc[2][j] = fma(w2, xv, acc[2][j]);
                        acc[3][j] = fma(w3, xv, acc[3][j]);
                    }
                }
            }
        }
        __syncthreads();
    }

    int gy = gy0 + pyt;
    #pragma unroll
    for (int i = 0; i < 4; ++i) {
        int co = co0 + tm * 4 + i;
        double bias = (double)b1[co];
        #pragma unroll
        for (int j = 0; j < 4; ++j) {
            int gx = gx0 + px0 + j;
            if (gy < HH && gx < WW) {
                double v = fmax(acc[i][j] + bias, 0.0);
                ib[(size_t)co * NPIX + gy * WW + gx] = v;
            }
        }
    }
}

// ---------------- 1x1 heads, f64, fused partial-reduce (mode 2) ----------------
#define HP 64
#define HCI 32
__global__ __launch_bounds__(128) void heads_fused_f64(
    const double* __restrict__ part, const float* __restrict__ b1,
    const float* __restrict__ w_loc, const float* __restrict__ b_loc,
    const float* __restrict__ w_score, const float* __restrict__ b_score,
    double* __restrict__ loc64, double* __restrict__ score64,
    float* __restrict__ out_loc, float* __restrict__ out_score) {
    __shared__ double xsh[HCI][HP];
    __shared__ double wsh[HEADCH][HCI];
    int bz = blockIdx.y;
    int n = bz;
    const size_t total = (size_t)NB * CMID * NPIX;
    const double* p0 = part + (size_t)bz * CMID * NPIX;
    const double* p1 = p0 + total;
    int p0i = blockIdx.x * HP;
    int tid = threadIdx.x;
    int pl = tid & 63;
    int g = tid >> 6;
    double acc[27] = {};

    for (int cc = 0; cc < CMID; cc += HCI) {
        for (int e = tid; e < HCI * HP; e += 128) {
            int p = e % HP;
            int ci = e / HP;
            int gp = p0i + p;
            double v = 0.0;
            if (gp < NPIX) {
                size_t off = (size_t)(cc + ci) * NPIX + gp;
                v = fmax(p0[off] + p1[off] + (double)b1[cc + ci], 0.0);
            }
            xsh[ci][p] = v;
        }
        for (int e = tid; e < HEADCH * HCI; e += 128) {
            int ci = e % HCI;
            int u = e / HCI;
            float wv = (u < LOCCH) ? w_loc[(size_t)u * CMID + cc + ci]
                                   : w_score[(size_t)(u - LOCCH) * CMID + cc + ci];
            wsh[u][ci] = (double)wv;
        }
        __syncthreads();
        for (int ci = 0; ci < HCI; ++ci) {
            double xv = xsh[ci][pl];
            #pragma unroll
            for (int o = 0; o < 27; ++o)
                acc[o] = fma(wsh[g * 27 + o][ci], xv, acc[o]);
        }
        __syncthreads();
    }

    int gp = p0i + pl;
    if (gp < NPIX) {
        #pragma unroll
        for (int o = 0; o < 27; ++o) {
            int u = g * 27 + o;
            if (u < LOCCH) {
                double v = acc[o] + (double)b_loc[u];
                loc64[(size_t)n * RR * 4 + (size_t)gp * 36 + u] = v;
                out_loc[(size_t)n * RR * 4 + (size_t)gp * 36 + u] = (float)v;
            } else {
                int us = u - LOCCH;
                double v = acc[o] + (double)b_score[us];
                score64[(size_t)n * RR * 2 + (size_t)gp * 18 + us] = v;
                out_score[(size_t)n * RR * 2 + (size_t)gp * 18 + us] = (float)v;
            }
        }
    }
}

// ---------------- 1x1 heads for fallback modes ----------------
__global__ __launch_bounds__(128) void heads_kernel_f64(
    const double* __restrict__ inter,
    const float* __restrict__ w_loc, const float* __restrict__ b_loc,
    const float* __restrict__ w_score, const float* __restrict__ b_score,
    double* __restrict__ loc64, double* __restrict__ score64,
    float* __restrict__ out_loc, float* __restrict__ out_score, int nbase) {
    __shared__ double xsh[HCI][HP];
    __shared__ double wsh[HEADCH][HCI];
    int bz = blockIdx.y;
    int n = nbase + bz;
    const double* ib = inter + (size_t)bz * CMID * NPIX;
    int p0 = blockIdx.x * HP;
    int tid = threadIdx.x;
    int pl = tid & 63;
    int g = tid >> 6;
    double acc[27] = {};

    for (int cc = 0; cc < CMID; cc += HCI) {
        for (int e = tid; e < HCI * HP; e += 128) {
            int p = e % HP;
            int ci = e / HP;
            int gp = p0 + p;
            xsh[ci][p] = (gp < NPIX) ? ib[(size_t)(cc + ci) * NPIX + gp] : 0.0;
        }
        for (int e = tid; e < HEADCH * HCI; e += 128) {
            int ci = e % HCI;
            int u = e / HCI;
            float wv = (u < LOCCH) ? w_loc[(size_t)u * CMID + cc + ci]
                                   : w_score[(size_t)(u - LOCCH) * CMID + cc + ci];
            wsh[u][ci] = (double)wv;
        }
        __syncthreads();
        for (int ci = 0; ci < HCI; ++ci) {
            double xv = xsh[ci][pl];
            #pragma unroll
            for (int o = 0; o < 27; ++o)
                acc[o] = fma(wsh[g * 27 + o][ci], xv, acc[o]);
        }
        __syncthreads();
    }

    int gp = p0 + pl;
    if (gp < NPIX) {
        #pragma unroll
        for (int o = 0; o < 27; ++o) {
            int u = g * 27 + o;
            if (u < LOCCH) {
                double v = acc[o] + (double)b_loc[u];
                loc64[(size_t)n * RR * 4 + (size_t)gp * 36 + u] = v;
                out_loc[(size_t)n * RR * 4 + (size_t)gp * 36 + u] = (float)v;
            } else {
                int us = u - LOCCH;
                double v = acc[o] + (double)b_score[us];
                score64[(size_t)n * RR * 2 + (size_t)gp * 18 + us] = v;
                out_score[(size_t)n * RR * 2 + (size_t)gp * 18 + us] = (float)v;
            }
        }
    }
}

// ---------------- anchors + decode + softmax-fg + keys, f64 ----------------
__global__ void box_kernel_f64_v2(const double* __restrict__ loc64,
                                  const double* __restrict__ score64,
                                  float* __restrict__ out_anchor,
                                  const int* __restrict__ imh_p, const int* __restrict__ imw_p,
                                  double* __restrict__ boxes, u64* __restrict__ keys) {
    int idx = blockIdx.x * 256 + threadIdx.x;
    if (idx >= NB * RR) return;
    int r = idx % RR;
    int a = r % AA;
    int pp = r / AA;
    int gy = pp / WW, gx = pp % WW;
    int ri = a / 3, si = a % 3;
    const double ratios[3] = {0.5, 1.0, 2.0};
    const double scales[3] = {8.0, 16.0, 32.0};
    double hh = 16.0 * sqrt(ratios[ri]) * scales[si];
    double ww = 16.0 * sqrt(1.0 / ratios[ri]) * scales[si];
    float sy = (float)(gy * 16), sx = (float)(gx * 16);
    float a0f = (float)(8.0 - hh * 0.5) + sy;
    float a1f = (float)(8.0 - ww * 0.5) + sx;
    float a2f = (float)(8.0 + hh * 0.5) + sy;
    float a3f = (float)(8.0 + ww * 0.5) + sx;
    if (idx < RR) {
        float* o = out_anchor + (size_t)r * 4;
        o[0] = a0f; o[1] = a1f; o[2] = a2f; o[3] = a3f;
    }
    double a0 = (double)a0f, a1 = (double)a1f, a2 = (double)a2f, a3 = (double)a3f;

    const double* l = loc64 + (size_t)idx * 4;
    double ah = a2 - a0, aw = a3 - a1;
    double acy = a0 + 0.5 * ah, acx = a1 + 0.5 * aw;
    double cy = l[0] * ah + acy, cx = l[1] * aw + acx;
    double h = exp(l[2]) * ah, w = exp(l[3]) * aw;
    double imh = (double)imh_p[0], imw = (double)imw_p[0];
    double y1 = fmin(fmax(cy - 0.5 * h, 0.0), imh);
    double x1 = fmin(fmax(cx - 0.5 * w, 0.0), imw);
    double y2 = fmin(fmax(cy + 0.5 * h, 0.0), imh);
    double x2 = fmin(fmax(cx + 0.5 * w, 0.0), imw);
    bool valid = ((y2 - y1) >= 16.0) && ((x2 - x1) >= 16.0);
    double* b = boxes + (size_t)idx * 4;
    b[0] = y1; b[1] = x1; b[2] = y2; b[3] = x2;
    double s0 = score64[(size_t)idx * 2];
    double s1 = score64[(size_t)idx * 2 + 1];
    double m = fmax(s0, s1);
    double e0 = exp(s0 - m), e1 = exp(s1 - m);
    double sc = valid ? (e1 / (e0 + e1)) : -__builtin_inf();
    u64 bits = (u64)__double_as_longlong(sc);
    u64 t = (bits >> 63) ? ~bits : (bits | 0x8000000000000000ull);
    keys[idx] = (t & 0xFFFFFFFFFFFF8000ull) | (u64)(32767 - r);
}

// ---------------- top-6000 select + full sort (per batch) ----------------
__global__ __launch_bounds__(1024) void select_kernel(
    const u64* __restrict__ keys, const double* __restrict__ boxes,
    double* __restrict__ sbox, int* __restrict__ sval) {
    __shared__ unsigned int hist[256];
    __shared__ u64 cand[8192];
    __shared__ unsigned int s_sel, s_base, s_cnt;
    int n = blockIdx.x;
    int tid = threadIdx.x;
    const u64* k = keys + (size_t)n * RR;

    u64 prefix = 0;
    unsigned int base = 0;
    for (int round = 0; round < 3; ++round) {
        if (tid < 256) hist[tid] = 0;
        __syncthreads();
        int shift_match = 64 - 8 * round;
        int shift_bin = 56 - 8 * round;
        for (int r = tid; r < RR; r += 1024) {
            u64 kv = k[r];
            bool match = (round == 0) || ((kv >> shift_match) == prefix);
            if (match) atomicAdd(&hist[(unsigned int)((kv >> shift_bin) & 0xFF)], 1u);
        }
        __syncthreads();
        if (tid == 0) {
            unsigned int c = base;
            int sel = 0;
            for (int v = 255; v >= 0; --v) {
                if (c + hist[v] >= PB) { sel = v; break; }
                c += hist[v];
            }
            s_sel = (unsigned int)sel;
            s_base = c;
        }
        __syncthreads();
        prefix = (prefix << 8) | (u64)s_sel;
        base = s_base;
        __syncthreads();
    }

    if (tid == 0) s_cnt = 0;
    __syncthreads();
    for (int r = tid; r < RR; r += 1024) {
        u64 kv = k[r];
        if ((kv >> 40) >= prefix) {
            unsigned int pos = atomicAdd(&s_cnt, 1u);
            if (pos < 8192u) cand[pos] = kv;
        }
    }
    __syncthreads();
    unsigned int cnt = s_cnt;
    if (cnt > 8192u) cnt = 8192u;
    for (unsigned int i = cnt + tid; i < 8192u; i += 1024u) cand[i] = 0ull;
    __syncthreads();

    for (unsigned int kk = 2; kk <= 8192; kk <<= 1) {
        for (unsigned int j = kk >> 1; j > 0; j >>= 1) {
            for (unsigned int t = tid; t < 4096; t += 1024) {
                unsigned int i = ((t & ~(j - 1)) << 1) | (t & (j - 1));
                unsigned int l = i | j;
                u64 a = cand[i], b = cand[l];
                bool desc = ((i & kk) == 0);
                if ((a < b) == desc) { cand[i] = b; cand[l] = a; }
            }
            __syncthreads();
        }
    }

    for (int s = tid; s < PB; s += 1024) {
        u64 kv = cand[s];
        int valid = (int)(kv >> 63);
        double b0 = 0.0, b1 = 0.0, b2 = 0.0, b3 = 0.0;
        if (valid) {
            int r = 32767 - (int)(kv & 0x7FFFull);
            const double* bp = boxes + ((size_t)n * RR + r) * 4;
            b0 = bp[0]; b1 = bp[1]; b2 = bp[2]; b3 = bp[3];
        }
        double* sp = sbox + ((size_t)n * PB + s) * 4;
        sp[0] = b0; sp[1] = b1; sp[2] = b2; sp[3] = b3;
        sval[n * PB + s] = valid;
    }
}

// ---------------- NMS phase 1: 1024x1024 suppression matrix ----------------
__global__ __launch_bounds__(256) void nms_matrix_v2(
    const double* __restrict__ sbox, unsigned int* __restrict__ sup) {
    __shared__ double jb[SUPK * 4];   // 32 KB
    int n = blockIdx.x >> 5;          // grid = NB * 32
    int rt = blockIdx.x & 31;
    int tid = threadIdx.x;

    for (int e = tid; e < SUPK * 4; e += 256)
        jb[e] = sbox[(size_t)n * PB * 4 + e];
    __syncthreads();

    int r = tid >> 3;
    int wq = tid & 7;
    int i = rt * 32 + r;
    const double* bi = &jb[(size_t)i * 4];
    double y1 = bi[0], x1 = bi[1], y2 = bi[2], x2 = bi[3];
    double ai = (y2 - y1) * (x2 - x1);
    unsigned int* srow = sup + ((size_t)n * SUPK + i) * KW1;

    #pragma unroll
    for (int q = 0; q < 4; ++q) {
        int w = wq * 4 + q;
        unsigned int m = 0;
        int jbase = w * 32;
        for (int b = 0; b < 32; ++b) {
            int j = jbase + b;
            if (j <= i) continue;
            const double* bj = &jb[(size_t)j * 4];
            double ty = fmax(y1, bj[0]);
            double tx = fmax(x1, bj[1]);
            double by = fmin(y2, bj[2]);
            double bx = fmin(x2, bj[3]);
            double ih = fmax(by - ty, 0.0);
            double iw = fmax(bx - tx, 0.0);
            double inter = ih * iw;
            double aj = (bj[2] - bj[0]) * (bj[3] - bj[1]);
            if (inter > 0.7 * (ai + aj - inter + 1e-9)) m |= (1u << b);
        }
        srow[w] = m;
    }
}

// ---------------- NMS phase 2: LDS-resident greedy scan, 1 wave ----------------
__global__ __launch_bounds__(64) void nms_scan_v2(
    const double* __restrict__ sbox, const int* __restrict__ sval,
    const unsigned int* __restrict__ sup,
    float* __restrict__ rois, float* __restrict__ rind) {
    __shared__ unsigned int supm[SUPK * KW1];   // 128 KB
    __shared__ unsigned int keep1[KW1];
    __shared__ unsigned int keep2[KW2];
    __shared__ int kidx[PA];
    __shared__ double bi4[4];
    int n = blockIdx.x;
    int lane = threadIdx.x;

    // stage sup matrix into LDS (coalesced uint4)
    const uint4* sg = (const uint4*)(sup + (size_t)n * SUPK * KW1);
    uint4* sd = (uint4*)supm;
    for (int e = lane; e < SUPK * KW1 / 4; e += 64)
        sd[e] = sg[e];
    if (lane < KW1) {
        unsigned int m = 0;
        const int* sv = sval + n * PB + lane * 32;
        for (int b = 0; b < 32; ++b)
            if (sv[b]) m |= (1u << b);
        keep1[lane] = m;
    }
    for (int w = lane; w < KW2; w += 64) keep2[w] = 0u;
    __syncthreads();

    int kc = 0;
    bool full = false;
    for (int wi = 0; wi < KW1 && !full; ++wi) {
        unsigned int word = keep1[wi];
        while (word) {
            int b = __ffs(word) - 1;
            int i = (wi << 5) + b;
            if (lane == 0) kidx[kc] = i;
            ++kc;
            if (kc >= PA) { full = true; break; }
            if (lane < KW1) keep1[lane] &= ~supm[i * KW1 + lane];
            __syncthreads();
            word = keep1[wi] & ((b >= 31) ? 0u : (0xFFFFFFFFu << (b + 1)));
        }
    }
    __syncthreads();

    if (!full) {
        // init keep2 for j >= SUPK: valid and not suppressed by any phase-1 kept box
        for (int j = SUPK + lane; j < PB; j += 64) {
            bool v = sval[n * PB + j] != 0;
            if (v) {
                const double* bj = sbox + ((size_t)n * PB + j) * 4;
                double jy1 = bj[0], jx1 = bj[1], jy2 = bj[2], jx2 = bj[3];
                double aj = (jy2 - jy1) * (jx2 - jx1);
                for (int p = 0; p < kc && v; ++p) {
                    const double* bp = sbox + ((size_t)n * PB + kidx[p]) * 4;
                    double ty = fmax(bp[0], jy1);
                    double tx = fmax(bp[1], jx1);
                    double by = fmin(bp[2], jy2);
                    double bx = fmin(bp[3], jx2);
                    double ih = fmax(by - ty, 0.0);
                    double iw = fmax(bx - tx, 0.0);
                    double inter = ih * iw;
                    double ai = (bp[2] - bp[0]) * (bp[3] - bp[1]);
                    if (inter > 0.7 * (ai + aj - inter + 1e-9)) v = false;
                }
                if (v) atomicOr(&keep2[(j - SUPK) >> 5], 1u << ((j - SUPK) & 31));
            }
        }
        __syncthreads();
        for (int wi = 0; wi < KW2 && !full; ++wi) {
            unsigned int word = keep2[wi];
            while (word) {
                int b = __ffs(word) - 1;
                int i = SUPK + (wi << 5) + b;
                if (lane == 0) {
                    kidx[kc] = i;
                    const double* bp = sbox + ((size_t)n * PB + i) * 4;
                    bi4[0] = bp[0]; bi4[1] = bp[1]; bi4[2] = bp[2]; bi4[3] = bp[3];
                }
                ++kc;
                if (kc >= PA) { full = true; break; }
                __syncthreads();
                double y1 = bi4[0], x1 = bi4[1], y2 = bi4[2], x2 = bi4[3];
                double ai = (y2 - y1) * (x2 - x1);
                for (int j = i + 1 + lane; j < PB; j += 64) {
                    int jj = j - SUPK;
                    if (!((keep2[jj >> 5] >> (jj & 31)) & 1u)) continue;
                    const double* bj = sbox + ((size_t)n * PB + j) * 4;
                    double ty = fmax(y1, bj[0]);
                    double tx = fmax(x1, bj[1]);
                    double by = fmin(y2, bj[2]);
                    double bx = fmin(x2, bj[3]);
                    double ih = fmax(by - ty, 0.0);
                    double iw = fmax(bx - tx, 0.0);
                    double inter = ih * iw;
                    double aj = (bj[2] - bj[0]) * (bj[3] - bj[1]);
                    if (inter > 0.7 * (ai + aj - inter + 1e-9))
                        atomicAnd(&keep2[jj >> 5], ~(1u << (jj & 31)));
                }
                __syncthreads();
                word = keep2[wi] & ((b >= 31) ? 0u : (0xFFFFFFFFu << (b + 1)));
            }
        }
    }
    __syncthreads();

    // gather rois from kept indices (parallel, off the critical chain)
    for (int p = lane; p < PA; p += 64) {
        float* rp = rois + ((size_t)n * PA + p) * 4;
        if (p < kc) {
            const double* bp = sbox + ((size_t)n * PB + kidx[p]) * 4;
            rp[0] = (float)bp[0]; rp[1] = (float)bp[1];
            rp[2] = (float)bp[2]; rp[3] = (float)bp[3];
        } else {
            rp[0] = 0.f; rp[1] = 0.f; rp[2] = 0.f; rp[3] = 0.f;
        }
        rind[n * PA + p] = (float)n;
    }
}

// ---------------- launch ----------------
extern "C" void kernel_launch(void* const* d_in, const int* in_sizes, int n_in,
                              void* d_out, int out_size, void* d_ws, size_t ws_size,
                              hipStream_t stream) {
    const float* x = (const float*)d_in[0];
    const float* w1 = (const float*)d_in[1];
    const float* b1 = (const float*)d_in[2];
    const float* w_score = (const float*)d_in[3];
    const float* b_score = (const float*)d_in[4];
    const float* w_loc = (const float*)d_in[5];
    const float* b_loc = (const float*)d_in[6];
    const int* img_h = (const int*)d_in[7];
    const int* img_w = (const int*)d_in[8];

    float* out = (float*)d_out;
    float* out_loc = out;
    float* out_score = out + 360000;
    float* out_rois = out + 540000;
    float* out_rind = out + 544800;
    float* out_anchor = out + 546000;

    const size_t interB = (size_t)NB * CMID * NPIX * 8;
    const size_t partB = 2 * interB;
    const size_t interB_serial = (size_t)CMID * NPIX * 8;
    const size_t restB = 2880000 + 1440000 + 2880000 + 720000 + 768000 + 96000;

    int mode;
    size_t convB;
    if (ws_size >= partB + restB) { mode = 2; convB = partB; }
    else if (ws_size >= interB + restB) { mode = 1; convB = interB; }
    else { mode = 0; convB = interB_serial; }

    char* p = (char*)d_ws;
    double* conv_buf = (double*)p; p += convB;
    double* loc64   = (double*)p; p += 2880000;
    double* score64 = (double*)p; p += 1440000;
    double* boxes64 = (double*)p; p += 2880000;
    u64*    keys    = (u64*)p;    p += 720000;
    double* sbox64  = (double*)p; p += 768000;
    int*    sval    = (int*)p;

    unsigned int* sup = (unsigned int*)conv_buf;   // 512 KB, conv_buf dead after heads

    if (mode == 2) {
        hipLaunchKernelGGL(conv3_f64_v9, dim3(49, 16, NB), dim3(128), 0, stream,
                           x, w1, conv_buf);
        hipLaunchKernelGGL(heads_fused_f64, dim3(40, NB), dim3(128), 0, stream,
                           conv_buf, b1, w_loc, b_loc, w_score, b_score,
                           loc64, score64, out_loc, out_score);
    } else if (mode == 1) {
        hipLaunchKernelGGL(conv3_f64_v3, dim3(49, 8, NB), dim3(256), 0, stream,
                           x, w1, b1, conv_buf, 0);
        hipLaunchKernelGGL(heads_kernel_f64, dim3(40, NB), dim3(128), 0, stream,
                           conv_buf, w_loc, b_loc, w_score, b_score,
                           loc64, score64, out_loc, out_score, 0);
    } else {
        for (int n = 0; n < NB; ++n) {
            hipLaunchKernelGGL(conv3_f64_v3, dim3(49, 8, 1), dim3(256), 0, stream,
                               x, w1, b1, conv_buf, n);
            hipLaunchKernelGGL(heads_kernel_f64, dim3(40, 1), dim3(128), 0, stream,
                               conv_buf, w_loc, b_loc, w_score, b_score,
                               loc64, score64, out_loc, out_score, n);
        }
    }

    hipLaunchKernelGGL(box_kernel_f64_v2, dim3((NB * RR + 255) / 256), dim3(256), 0, stream,
                       loc64, score64, out_anchor, img_h, img_w, boxes64, keys);
    hipLaunchKernelGGL(select_kernel, dim3(4), dim3(1024), 0, stream, keys, boxes64, sbox64, sval);
    hipLaunchKernelGGL(nms_matrix_v2, dim3(NB * 32), dim3(256), 0, stream, sbox64, sup);
    hipLaunchKernelGGL(nms_scan_v2, dim3(NB), dim3(64), 0, stream, sbox64, sval, sup,
                       out_rois, out_rind);
}

// Round 17
// 1538.281 us; speedup vs baseline: 1.3637x; 1.0676x over previous
//
#include <hip/hip_runtime.h>
#include <stdint.h>
#include <math.h>

#define NB 4
#define CIN 512
#define CMID 512
#define HH 50
#define WW 50
#define NPIX 2500
#define AA 9
#define RR 22500
#define PB 6000
#define PA 300
#define LOCCH 36
#define SCORECH 18
#define HEADCH 54
#define CI_T 8
#define CI_T2 4
#define SUPK 1024
#define KW1 32
#define KW2 ((PB - SUPK + 31) / 32)

typedef unsigned long long u64;

// ---------------- conv v9 (R12/R16-verified): split-K=2, zero-arithmetic staging ----
__global__ __launch_bounds__(128) void conv3_f64_v9(
    const float* __restrict__ x, const float* __restrict__ w1,
    double* __restrict__ part) {
    __shared__ __align__(16) double xs[CI_T2 * 100];
    __shared__ __align__(16) float wsf[CI_T2 * 9 * 68];

    int tile = blockIdx.x;
    int ty = tile / 7, tx = tile % 7;
    int yy = blockIdx.y;
    int co0 = (yy & 7) * 64;
    int kk = yy >> 3;
    int bz = blockIdx.z;
    int tid = threadIdx.x;
    int tm = tid & 15;
    int pyt = tid >> 4;
    int gy0 = ty * 8, gx0 = tx * 8;
    const float* xb = x + (size_t)bz * CIN * NPIX;
    int cc0 = kk * 256;

    int xg[4];
    #pragma unroll
    for (int k = 0; k < 4; ++k) {
        int e = tid + k * 128;
        if (e < CI_T2 * 100) {
            int ci = e / 100, rc = e % 100;
            int row = rc / 10, col = rc % 10;
            int gy = gy0 - 1 + row, gx = gx0 - 1 + col;
            xg[k] = (gy >= 0 && gy < HH && gx >= 0 && gx < WW)
                        ? (ci * NPIX + gy * WW + gx) : -1;
        } else {
            xg[k] = -1;
        }
    }
    int wm = tid >> 1;
    int wq0 = (tid & 1) * 18;
    const float* wrow = w1 + (size_t)(co0 + wm) * (CIN * 9) + wq0;
    float* wdst = &wsf[wq0 * 68 + wm];

    double acc[4][8] = {};

    for (int cc = cc0; cc < cc0 + 256; cc += CI_T2) {
        size_t xoff = (size_t)cc * NPIX;
        #pragma unroll
        for (int k = 0; k < 4; ++k) {
            int e = tid + k * 128;
            if (e < CI_T2 * 100) {
                float v = (xg[k] >= 0) ? xb[xoff + xg[k]] : 0.f;
                xs[e] = (double)v;
            }
        }
        {
            const float* ws = wrow + (size_t)cc * 9;
            #pragma unroll
            for (int k = 0; k < 18; ++k)
                wdst[k * 68] = ws[k];
        }
        __syncthreads();

        for (int ci = 0; ci < CI_T2; ++ci) {
            #pragma unroll
            for (int ky = 0; ky < 3; ++ky) {
                double xa[10];
                const double* xr = &xs[ci * 100 + (pyt + ky) * 10];
                #pragma unroll
                for (int t = 0; t < 5; ++t)
                    *(double2*)&xa[2 * t] = *(const double2*)&xr[2 * t];
                #pragma unroll
                for (int kx = 0; kx < 3; ++kx) {
                    float4 wf = *(const float4*)&wsf[(ci * 9 + ky * 3 + kx) * 68 + tm * 4];
                    double w0 = (double)wf.x, w1v = (double)wf.y;
                    double w2 = (double)wf.z, w3 = (double)wf.w;
                    #pragma unroll
                    for (int j = 0; j < 8; ++j) {
                        double xv = xa[kx + j];
                        acc[0][j] = fma(w0, xv, acc[0][j]);
                        acc[1][j] = fma(w1v, xv, acc[1][j]);
                        acc[2][j] = fma(w2, xv, acc[2][j]);
                        acc[3][j] = fma(w3, xv, acc[3][j]);
                    }
                }
            }
        }
        __syncthreads();
    }

    int gy = gy0 + pyt;
    if (gy < HH) {
        double* pb = part + (size_t)kk * NB * CMID * NPIX + (size_t)bz * CMID * NPIX;
        #pragma unroll
        for (int i = 0; i < 4; ++i) {
            int co = co0 + tm * 4 + i;
            #pragma unroll
            for (int j = 0; j < 8; ++j) {
                int gx = gx0 + j;
                if (gx < WW)
                    pb[(size_t)co * NPIX + gy * WW + gx] = acc[i][j];
            }
        }
    }
}

// ---------------- fallback conv (R5's v3, bit-verified) ----------------
__global__ __launch_bounds__(256) void conv3_f64_v3(
    const float* __restrict__ x, const float* __restrict__ w1,
    const float* __restrict__ b1, double* __restrict__ inter, int nbase) {
    __shared__ __align__(16) double xs[CI_T][10][10];
    __shared__ __align__(16) float wsf[CI_T * 9][68];

    int tile = blockIdx.x;
    int ty = tile / 7, tx = tile % 7;
    int co0 = blockIdx.y * 64;
    int bz = blockIdx.z;
    int n = nbase + bz;
    int tid = threadIdx.x;
    int tm = tid & 15;
    int tp = tid >> 4;
    int pyt = tp >> 1;
    int px0 = (tp & 1) * 4;
    int gy0 = ty * 8, gx0 = tx * 8;
    const float* xb = x + (size_t)n * CIN * NPIX;
    double* ib = inter + (size_t)bz * CMID * NPIX;

    double acc[4][4] = {};

    for (int cc = 0; cc < CIN; cc += CI_T) {
        for (int e = tid; e < CI_T * 100; e += 256) {
            int ci = e / 100, rc = e % 100;
            int row = rc / 10, col = rc % 10;
            int gy = gy0 - 1 + row, gx = gx0 - 1 + col;
            float v = 0.f;
            if (gy >= 0 && gy < HH && gx >= 0 && gx < WW)
                v = xb[(size_t)(cc + ci) * NPIX + gy * WW + gx];
            xs[ci][row][col] = (double)v;
        }
        for (int e = tid; e < 64 * 72; e += 256) {
            int m = e / 72, q = e % 72;
            wsf[q][m] = w1[((size_t)(co0 + m) * CIN + cc) * 9 + q];
        }
        __syncthreads();

        for (int ci = 0; ci < CI_T; ++ci) {
            #pragma unroll
            for (int ky = 0; ky < 3; ++ky) {
                double xa[6];
                const double* xrow = &xs[ci][pyt + ky][px0];
                *(double2*)&xa[0] = *(const double2*)&xrow[0];
                *(double2*)&xa[2] = *(const double2*)&xrow[2];
                *(double2*)&xa[4] = *(const double2*)&xrow[4];
                #pragma unroll
                for (int kx = 0; kx < 3; ++kx) {
                    float4 wf = *(const float4*)&wsf[ci * 9 + ky * 3 + kx][tm * 4];
                    double w0 = (double)wf.x, w1v = (double)wf.y;
                    double w2 = (double)wf.z, w3 = (double)wf.w;
                    #pragma unroll
                    for (int j = 0; j < 4; ++j) {
                        double xv = xa[kx + j];
                        acc[0][j] = fma(w0, xv, acc[0][j]);
                        acc[1][j] = fma(w1v, xv, acc[1][j]);
                        acc[2][j] = fma(w2, xv, acc[2][j]);
                        acc[3][j] = fma(w3, xv, acc[3][j]);
                    }
                }
            }
        }
        __syncthreads();
    }

    int gy = gy0 + pyt;
    #pragma unroll
    for (int i = 0; i < 4; ++i) {
        int co = co0 + tm * 4 + i;
        double bias = (double)b1[co];
        #pragma unroll
        for (int j = 0; j < 4; ++j) {
            int gx = gx0 + px0 + j;
            if (gy < HH && gx < WW) {
                double v = fmax(acc[i][j] + bias, 0.0);
                ib[(size_t)co * NPIX + gy * WW + gx] = v;
            }
        }
    }
}

// ---------------- heads split-K part (mode 2): 256 channels per block ----------------
// grid (40, NB, 2), block 128. ks=0 -> partial into loc64/score64 (no head bias);
// ks=1 -> partial into hp1[n][gp][u] (aliases boxes64+keys+sbox dead region).
#define HP 64
#define HCI 32
__global__ __launch_bounds__(128) void heads_part_f64(
    const double* __restrict__ part, const float* __restrict__ b1,
    const float* __restrict__ w_loc, const float* __restrict__ w_score,
    double* __restrict__ loc64, double* __restrict__ score64,
    double* __restrict__ hp1) {
    __shared__ double xsh[HCI][HP];
    __shared__ double wsh[HEADCH][HCI];
    int bz = blockIdx.y;
    int n = bz;
    int ks = blockIdx.z;
    const size_t total = (size_t)NB * CMID * NPIX;
    const double* p0 = part + (size_t)bz * CMID * NPIX;
    const double* p1 = p0 + total;
    int p0i = blockIdx.x * HP;
    int tid = threadIdx.x;
    int pl = tid & 63;
    int g = tid >> 6;
    int cbase = ks * 256;
    double acc[27] = {};

    for (int cc = cbase; cc < cbase + 256; cc += HCI) {
        for (int e = tid; e < HCI * HP; e += 128) {
            int p = e % HP;
            int ci = e / HP;
            int gp = p0i + p;
            double v = 0.0;
            if (gp < NPIX) {
                size_t off = (size_t)(cc + ci) * NPIX + gp;
                v = fmax(p0[off] + p1[off] + (double)b1[cc + ci], 0.0);
            }
            xsh[ci][p] = v;
        }
        for (int e = tid; e < HEADCH * HCI; e += 128) {
            int ci = e % HCI;
            int u = e / HCI;
            float wv = (u < LOCCH) ? w_loc[(size_t)u * CMID + cc + ci]
                                   : w_score[(size_t)(u - LOCCH) * CMID + cc + ci];
            wsh[u][ci] = (double)wv;
        }
        __syncthreads();
        for (int ci = 0; ci < HCI; ++ci) {
            double xv = xsh[ci][pl];
            #pragma unroll
            for (int o = 0; o < 27; ++o)
                acc[o] = fma(wsh[g * 27 + o][ci], xv, acc[o]);
        }
        __syncthreads();
    }

    int gp = p0i + pl;
    if (gp < NPIX) {
        if (ks == 0) {
            #pragma unroll
            for (int o = 0; o < 27; ++o) {
                int u = g * 27 + o;
                if (u < LOCCH)
                    loc64[(size_t)n * RR * 4 + (size_t)gp * 36 + u] = acc[o];
                else
                    score64[(size_t)n * RR * 2 + (size_t)gp * 18 + (u - LOCCH)] = acc[o];
            }
        } else {
            double* hp = hp1 + ((size_t)n * NPIX + gp) * HEADCH;
            #pragma unroll
            for (int o = 0; o < 27; ++o)
                hp[g * 27 + o] = acc[o];
        }
    }
}

// ---------------- heads reduce: final = part0 + part1 + bias ----------------
__global__ void heads_reduce(const double* __restrict__ hp1,
                             const float* __restrict__ b_loc,
                             const float* __restrict__ b_score,
                             double* __restrict__ loc64, double* __restrict__ score64,
                             float* __restrict__ out_loc, float* __restrict__ out_score) {
    int idx = blockIdx.x * 256 + threadIdx.x;
    if (idx >= NB * NPIX * HEADCH) return;
    int u = idx % HEADCH;
    int gp = (idx / HEADCH) % NPIX;
    int n = idx / (HEADCH * NPIX);
    double v1 = hp1[idx];
    if (u < LOCCH) {
        size_t o = (size_t)n * RR * 4 + (size_t)gp * 36 + u;
        double v = loc64[o] + v1 + (double)b_loc[u];
        loc64[o] = v;
        out_loc[o] = (float)v;
    } else {
        int us = u - LOCCH;
        size_t o = (size_t)n * RR * 2 + (size_t)gp * 18 + us;
        double v = score64[o] + v1 + (double)b_score[us];
        score64[o] = v;
        out_score[o] = (float)v;
    }
}

// ---------------- 1x1 heads for fallback modes ----------------
__global__ __launch_bounds__(128) void heads_kernel_f64(
    const double* __restrict__ inter,
    const float* __restrict__ w_loc, const float* __restrict__ b_loc,
    const float* __restrict__ w_score, const float* __restrict__ b_score,
    double* __restrict__ loc64, double* __restrict__ score64,
    float* __restrict__ out_loc, float* __restrict__ out_score, int nbase) {
    __shared__ double xsh[HCI][HP];
    __shared__ double wsh[HEADCH][HCI];
    int bz = blockIdx.y;
    int n = nbase + bz;
    const double* ib = inter + (size_t)bz * CMID * NPIX;
    int p0 = blockIdx.x * HP;
    int tid = threadIdx.x;
    int pl = tid & 63;
    int g = tid >> 6;
    double acc[27] = {};

    for (int cc = 0; cc < CMID; cc += HCI) {
        for (int e = tid; e < HCI * HP; e += 128) {
            int p = e % HP;
            int ci = e / HP;
            int gp = p0 + p;
            xsh[ci][p] = (gp < NPIX) ? ib[(size_t)(cc + ci) * NPIX + gp] : 0.0;
        }
        for (int e = tid; e < HEADCH * HCI; e += 128) {
            int ci = e % HCI;
            int u = e / HCI;
            float wv = (u < LOCCH) ? w_loc[(size_t)u * CMID + cc + ci]
                                   : w_score[(size_t)(u - LOCCH) * CMID + cc + ci];
            wsh[u][ci] = (double)wv;
        }
        __syncthreads();
        for (int ci = 0; ci < HCI; ++ci) {
            double xv = xsh[ci][pl];
            #pragma unroll
            for (int o = 0; o < 27; ++o)
                acc[o] = fma(wsh[g * 27 + o][ci], xv, acc[o]);
        }
        __syncthreads();
    }

    int gp = p0 + pl;
    if (gp < NPIX) {
        #pragma unroll
        for (int o = 0; o < 27; ++o) {
            int u = g * 27 + o;
            if (u < LOCCH) {
                double v = acc[o] + (double)b_loc[u];
                loc64[(size_t)n * RR * 4 + (size_t)gp * 36 + u] = v;
                out_loc[(size_t)n * RR * 4 + (size_t)gp * 36 + u] = (float)v;
            } else {
                int us = u - LOCCH;
                double v = acc[o] + (double)b_score[us];
                score64[(size_t)n * RR * 2 + (size_t)gp * 18 + us] = v;
                out_score[(size_t)n * RR * 2 + (size_t)gp * 18 + us] = (float)v;
            }
        }
    }
}

// ---------------- anchors + decode + softmax-fg + keys, f64 ----------------
__global__ void box_kernel_f64_v2(const double* __restrict__ loc64,
                                  const double* __restrict__ score64,
                                  float* __restrict__ out_anchor,
                                  const int* __restrict__ imh_p, const int* __restrict__ imw_p,
                                  double* __restrict__ boxes, u64* __restrict__ keys) {
    int idx = blockIdx.x * 256 + threadIdx.x;
    if (idx >= NB * RR) return;
    int r = idx % RR;
    int a = r % AA;
    int pp = r / AA;
    int gy = pp / WW, gx = pp % WW;
    int ri = a / 3, si = a % 3;
    const double ratios[3] = {0.5, 1.0, 2.0};
    const double scales[3] = {8.0, 16.0, 32.0};
    double hh = 16.0 * sqrt(ratios[ri]) * scales[si];
    double ww = 16.0 * sqrt(1.0 / ratios[ri]) * scales[si];
    float sy = (float)(gy * 16), sx = (float)(gx * 16);
    float a0f = (float)(8.0 - hh * 0.5) + sy;
    float a1f = (float)(8.0 - ww * 0.5) + sx;
    float a2f = (float)(8.0 + hh * 0.5) + sy;
    float a3f = (float)(8.0 + ww * 0.5) + sx;
    if (idx < RR) {
        float* o = out_anchor + (size_t)r * 4;
        o[0] = a0f; o[1] = a1f; o[2] = a2f; o[3] = a3f;
    }
    double a0 = (double)a0f, a1 = (double)a1f, a2 = (double)a2f, a3 = (double)a3f;

    const double* l = loc64 + (size_t)idx * 4;
    double ah = a2 - a0, aw = a3 - a1;
    double acy = a0 + 0.5 * ah, acx = a1 + 0.5 * aw;
    double cy = l[0] * ah + acy, cx = l[1] * aw + acx;
    double h = exp(l[2]) * ah, w = exp(l[3]) * aw;
    double imh = (double)imh_p[0], imw = (double)imw_p[0];
    double y1 = fmin(fmax(cy - 0.5 * h, 0.0), imh);
    double x1 = fmin(fmax(cx - 0.5 * w, 0.0), imw);
    double y2 = fmin(fmax(cy + 0.5 * h, 0.0), imh);
    double x2 = fmin(fmax(cx + 0.5 * w, 0.0), imw);
    bool valid = ((y2 - y1) >= 16.0) && ((x2 - x1) >= 16.0);
    double* b = boxes + (size_t)idx * 4;
    b[0] = y1; b[1] = x1; b[2] = y2; b[3] = x2;
    double s0 = score64[(size_t)idx * 2];
    double s1 = score64[(size_t)idx * 2 + 1];
    double m = fmax(s0, s1);
    double e0 = exp(s0 - m), e1 = exp(s1 - m);
    double sc = valid ? (e1 / (e0 + e1)) : -__builtin_inf();
    u64 bits = (u64)__double_as_longlong(sc);
    u64 t = (bits >> 63) ? ~bits : (bits | 0x8000000000000000ull);
    keys[idx] = (t & 0xFFFFFFFFFFFF8000ull) | (u64)(32767 - r);
}

// ---------------- top-6000 select + full sort (per batch) ----------------
__global__ __launch_bounds__(1024) void select_kernel(
    const u64* __restrict__ keys, const double* __restrict__ boxes,
    double* __restrict__ sbox, int* __restrict__ sval) {
    __shared__ unsigned int hist[256];
    __shared__ u64 cand[8192];
    __shared__ unsigned int s_sel, s_base, s_cnt;
    int n = blockIdx.x;
    int tid = threadIdx.x;
    const u64* k = keys + (size_t)n * RR;

    u64 prefix = 0;
    unsigned int base = 0;
    for (int round = 0; round < 3; ++round) {
        if (tid < 256) hist[tid] = 0;
        __syncthreads();
        int shift_match = 64 - 8 * round;
        int shift_bin = 56 - 8 * round;
        for (int r = tid; r < RR; r += 1024) {
            u64 kv = k[r];
            bool match = (round == 0) || ((kv >> shift_match) == prefix);
            if (match) atomicAdd(&hist[(unsigned int)((kv >> shift_bin) & 0xFF)], 1u);
        }
        __syncthreads();
        if (tid == 0) {
            unsigned int c = base;
            int sel = 0;
            for (int v = 255; v >= 0; --v) {
                if (c + hist[v] >= PB) { sel = v; break; }
                c += hist[v];
            }
            s_sel = (unsigned int)sel;
            s_base = c;
        }
        __syncthreads();
        prefix = (prefix << 8) | (u64)s_sel;
        base = s_base;
        __syncthreads();
    }

    if (tid == 0) s_cnt = 0;
    __syncthreads();
    for (int r = tid; r < RR; r += 1024) {
        u64 kv = k[r];
        if ((kv >> 40) >= prefix) {
            unsigned int pos = atomicAdd(&s_cnt, 1u);
            if (pos < 8192u) cand[pos] = kv;
        }
    }
    __syncthreads();
    unsigned int cnt = s_cnt;
    if (cnt > 8192u) cnt = 8192u;
    for (unsigned int i = cnt + tid; i < 8192u; i += 1024u) cand[i] = 0ull;
    __syncthreads();

    for (unsigned int kk = 2; kk <= 8192; kk <<= 1) {
        for (unsigned int j = kk >> 1; j > 0; j >>= 1) {
            for (unsigned int t = tid; t < 4096; t += 1024) {
                unsigned int i = ((t & ~(j - 1)) << 1) | (t & (j - 1));
                unsigned int l = i | j;
                u64 a = cand[i], b = cand[l];
                bool desc = ((i & kk) == 0);
                if ((a < b) == desc) { cand[i] = b; cand[l] = a; }
            }
            __syncthreads();
        }
    }

    for (int s = tid; s < PB; s += 1024) {
        u64 kv = cand[s];
        int valid = (int)(kv >> 63);
        double b0 = 0.0, b1 = 0.0, b2 = 0.0, b3 = 0.0;
        if (valid) {
            int r = 32767 - (int)(kv & 0x7FFFull);
            const double* bp = boxes + ((size_t)n * RR + r) * 4;
            b0 = bp[0]; b1 = bp[1]; b2 = bp[2]; b3 = bp[3];
        }
        double* sp = sbox + ((size_t)n * PB + s) * 4;
        sp[0] = b0; sp[1] = b1; sp[2] = b2; sp[3] = b3;
        sval[n * PB + s] = valid;
    }
}

// ---------------- NMS phase 1: 1024x1024 suppression matrix ----------------
__global__ __launch_bounds__(256) void nms_matrix_v2(
    const double* __restrict__ sbox, unsigned int* __restrict__ sup) {
    __shared__ double jb[SUPK * 4];
    int n = blockIdx.x >> 5;
    int rt = blockIdx.x & 31;
    int tid = threadIdx.x;

    for (int e = tid; e < SUPK * 4; e += 256)
        jb[e] = sbox[(size_t)n * PB * 4 + e];
    __syncthreads();

    int r = tid >> 3;
    int wq = tid & 7;
    int i = rt * 32 + r;
    const double* bi = &jb[(size_t)i * 4];
    double y1 = bi[0], x1 = bi[1], y2 = bi[2], x2 = bi[3];
    double ai = (y2 - y1) * (x2 - x1);
    unsigned int* srow = sup + ((size_t)n * SUPK + i) * KW1;

    #pragma unroll
    for (int q = 0; q < 4; ++q) {
        int w = wq * 4 + q;
        unsigned int m = 0;
        int jbase = w * 32;
        for (int b = 0; b < 32; ++b) {
            int j = jbase + b;
            if (j <= i) continue;
            const double* bj = &jb[(size_t)j * 4];
            double ty = fmax(y1, bj[0]);
            double tx = fmax(x1, bj[1]);
            double by = fmin(y2, bj[2]);
            double bx = fmin(x2, bj[3]);
            double ih = fmax(by - ty, 0.0);
            double iw = fmax(bx - tx, 0.0);
            double inter = ih * iw;
            double aj = (bj[2] - bj[0]) * (bj[3] - bj[1]);
            if (inter > 0.7 * (ai + aj - inter + 1e-9)) m |= (1u << b);
        }
        srow[w] = m;
    }
}

// ---------------- NMS phase 2: LDS-resident greedy scan, 1 wave ----------------
__global__ __launch_bounds__(64) void nms_scan_v2(
    const double* __restrict__ sbox, const int* __restrict__ sval,
    const unsigned int* __restrict__ sup,
    float* __restrict__ rois, float* __restrict__ rind) {
    __shared__ unsigned int supm[SUPK * KW1];
    __shared__ unsigned int keep1[KW1];
    __shared__ unsigned int keep2[KW2];
    __shared__ int kidx[PA];
    __shared__ double bi4[4];
    int n = blockIdx.x;
    int lane = threadIdx.x;

    const uint4* sg = (const uint4*)(sup + (size_t)n * SUPK * KW1);
    uint4* sd = (uint4*)supm;
    for (int e = lane; e < SUPK * KW1 / 4; e += 64)
        sd[e] = sg[e];
    if (lane < KW1) {
        unsigned int m = 0;
        const int* sv = sval + n * PB + lane * 32;
        for (int b = 0; b < 32; ++b)
            if (sv[b]) m |= (1u << b);
        keep1[lane] = m;
    }
    for (int w = lane; w < KW2; w += 64) keep2[w] = 0u;
    __syncthreads();

    int kc = 0;
    bool full = false;
    for (int wi = 0; wi < KW1 && !full; ++wi) {
        unsigned int word = keep1[wi];
        while (word) {
            int b = __ffs(word) - 1;
            int i = (wi << 5) + b;
            if (lane == 0) kidx[kc] = i;
            ++kc;
            if (kc >= PA) { full = true; break; }
            if (lane < KW1) keep1[lane] &= ~supm[i * KW1 + lane];
            __syncthreads();
            word = keep1[wi] & ((b >= 31) ? 0u : (0xFFFFFFFFu << (b + 1)));
        }
    }
    __syncthreads();

    if (!full) {
        for (int j = SUPK + lane; j < PB; j += 64) {
            bool v = sval[n * PB + j] != 0;
            if (v) {
                const double* bj = sbox + ((size_t)n * PB + j) * 4;
                double jy1 = bj[0], jx1 = bj[1], jy2 = bj[2], jx2 = bj[3];
                double aj = (jy2 - jy1) * (jx2 - jx1);
                for (int p = 0; p < kc && v; ++p) {
                    const double* bp = sbox + ((size_t)n * PB + kidx[p]) * 4;
                    double ty = fmax(bp[0], jy1);
                    double tx = fmax(bp[1], jx1);
                    double by = fmin(bp[2], jy2);
                    double bx = fmin(bp[3], jx2);
                    double ih = fmax(by - ty, 0.0);
                    double iw = fmax(bx - tx, 0.0);
                    double inter = ih * iw;
                    double ai = (bp[2] - bp[0]) * (bp[3] - bp[1]);
                    if (inter > 0.7 * (ai + aj - inter + 1e-9)) v = false;
                }
                if (v) atomicOr(&keep2[(j - SUPK) >> 5], 1u << ((j - SUPK) & 31));
            }
        }
        __syncthreads();
        for (int wi = 0; wi < KW2 && !full; ++wi) {
            unsigned int word = keep2[wi];
            while (word) {
                int b = __ffs(word) - 1;
                int i = SUPK + (wi << 5) + b;
                if (lane == 0) {
                    kidx[kc] = i;
                    const double* bp = sbox + ((size_t)n * PB + i) * 4;
                    bi4[0] = bp[0]; bi4[1] = bp[1]; bi4[2] = bp[2]; bi4[3] = bp[3];
                }
                ++kc;
                if (kc >= PA) { full = true; break; }
                __syncthreads();
                double y1 = bi4[0], x1 = bi4[1], y2 = bi4[2], x2 = bi4[3];
                double ai = (y2 - y1) * (x2 - x1);
                for (int j = i + 1 + lane; j < PB; j += 64) {
                    int jj = j - SUPK;
                    if (!((keep2[jj >> 5] >> (jj & 31)) & 1u)) continue;
                    const double* bj = sbox + ((size_t)n * PB + j) * 4;
                    double ty = fmax(y1, bj[0]);
                    double tx = fmax(x1, bj[1]);
                    double by = fmin(y2, bj[2]);
                    double bx = fmin(x2, bj[3]);
                    double ih = fmax(by - ty, 0.0);
                    double iw = fmax(bx - tx, 0.0);
                    double inter = ih * iw;
                    double aj = (bj[2] - bj[0]) * (bj[3] - bj[1]);
                    if (inter > 0.7 * (ai + aj - inter + 1e-9))
                        atomicAnd(&keep2[jj >> 5], ~(1u << (jj & 31)));
                }
                __syncthreads();
                word = keep2[wi] & ((b >= 31) ? 0u : (0xFFFFFFFFu << (b + 1)));
            }
        }
    }
    __syncthreads();

    for (int p = lane; p < PA; p += 64) {
        float* rp = rois + ((size_t)n * PA + p) * 4;
        if (p < kc) {
            const double* bp = sbox + ((size_t)n * PB + kidx[p]) * 4;
            rp[0] = (float)bp[0]; rp[1] = (float)bp[1];
            rp[2] = (float)bp[2]; rp[3] = (float)bp[3];
        } else {
            rp[0] = 0.f; rp[1] = 0.f; rp[2] = 0.f; rp[3] = 0.f;
        }
        rind[n * PA + p] = (float)n;
    }
}

// ---------------- launch ----------------
extern "C" void kernel_launch(void* const* d_in, const int* in_sizes, int n_in,
                              void* d_out, int out_size, void* d_ws, size_t ws_size,
                              hipStream_t stream) {
    const float* x = (const float*)d_in[0];
    const float* w1 = (const float*)d_in[1];
    const float* b1 = (const float*)d_in[2];
    const float* w_score = (const float*)d_in[3];
    const float* b_score = (const float*)d_in[4];
    const float* w_loc = (const float*)d_in[5];
    const float* b_loc = (const float*)d_in[6];
    const int* img_h = (const int*)d_in[7];
    const int* img_w = (const int*)d_in[8];

    float* out = (float*)d_out;
    float* out_loc = out;
    float* out_score = out + 360000;
    float* out_rois = out + 540000;
    float* out_rind = out + 544800;
    float* out_anchor = out + 546000;

    const size_t interB = (size_t)NB * CMID * NPIX * 8;
    const size_t partB = 2 * interB;
    const size_t interB_serial = (size_t)CMID * NPIX * 8;
    const size_t restB = 2880000 + 1440000 + 2880000 + 720000 + 768000 + 96000;

    int mode;
    size_t convB;
    if (ws_size >= partB + restB) { mode = 2; convB = partB; }
    else if (ws_size >= interB + restB) { mode = 1; convB = interB; }
    else { mode = 0; convB = interB_serial; }

    char* p = (char*)d_ws;
    double* conv_buf = (double*)p; p += convB;
    double* loc64   = (double*)p; p += 2880000;
    double* score64 = (double*)p; p += 1440000;
    double* boxes64 = (double*)p; p += 2880000;
    u64*    keys    = (u64*)p;    p += 720000;
    double* sbox64  = (double*)p; p += 768000;
    int*    sval    = (int*)p;

    unsigned int* sup = (unsigned int*)conv_buf;   // 512 KB, conv_buf dead after heads
    double* hp1 = boxes64;                         // 4.32 MB over boxes64+keys+sbox (dead until box/select)

    if (mode == 2) {
        hipLaunchKernelGGL(conv3_f64_v9, dim3(49, 16, NB), dim3(128), 0, stream,
                           x, w1, conv_buf);
        hipLaunchKernelGGL(heads_part_f64, dim3(40, NB, 2), dim3(128), 0, stream,
                           conv_buf, b1, w_loc, w_score, loc64, score64, hp1);
        hipLaunchKernelGGL(heads_reduce, dim3((NB * NPIX * HEADCH + 255) / 256), dim3(256),
                           0, stream, hp1, b_loc, b_score, loc64, score64,
                           out_loc, out_score);
    } else if (mode == 1) {
        hipLaunchKernelGGL(conv3_f64_v3, dim3(49, 8, NB), dim3(256), 0, stream,
                           x, w1, b1, conv_buf, 0);
        hipLaunchKernelGGL(heads_kernel_f64, dim3(40, NB), dim3(128), 0, stream,
                           conv_buf, w_loc, b_loc, w_score, b_score,
                           loc64, score64, out_loc, out_score, 0);
    } else {
        for (int n = 0; n < NB; ++n) {
            hipLaunchKernelGGL(conv3_f64_v3, dim3(49, 8, 1), dim3(256), 0, stream,
                               x, w1, b1, conv_buf, n);
            hipLaunchKernelGGL(heads_kernel_f64, dim3(40, 1), dim3(128), 0, stream,
                               conv_buf, w_loc, b_loc, w_score, b_score,
                               loc64, score64, out_loc, out_score, n);
        }
    }

    hipLaunchKernelGGL(box_kernel_f64_v2, dim3((NB * RR + 255) / 256), dim3(256), 0, stream,
                       loc64, score64, out_anchor, img_h, img_w, boxes64, keys);
    hipLaunchKernelGGL(select_kernel, dim3(4), dim3(1024), 0, stream, keys, boxes64, sbox64, sval);
    hipLaunchKernelGGL(nms_matrix_v2, dim3(NB * 32), dim3(256), 0, stream, sbox64, sup);
    hipLaunchKernelGGL(nms_scan_v2, dim3(NB), dim3(64), 0, stream, sbox64, sval, sup,
                       out_rois, out_rind);
}